// Round 1
// baseline (1819.424 us; speedup 1.0000x reference)
//
#include <hip/hip_runtime.h>
#include <math.h>

#define N_NODES 100000
#define E_EDGES 3200000
#define IN_DIM_ 128
#define HID_ 64
#define BN_EPS_ 1e-5f

// ---------------- degree / dinv ----------------

__global__ __launch_bounds__(256) void deg_kernel(const int* __restrict__ dst,
                                                  int* __restrict__ deg, int E) {
    int e = blockIdx.x * 256 + threadIdx.x;
    if (e < E) atomicAdd(&deg[dst[e]], 1);
}

__global__ __launch_bounds__(256) void dinv_kernel(const int* __restrict__ deg,
                                                   float* __restrict__ dinv, int n) {
    int i = blockIdx.x * 256 + threadIdx.x;
    if (i < n) dinv[i] = rsqrtf((float)deg[i] + 1.0f);
}

// ---------------- hs = (X @ W) * dinv[row] ----------------
// Block = 256 threads, 16 rows per block. W (K x 64) staged in LDS,
// X tile (16 x K) staged in LDS. Thread (rsub = tid>>6, j = tid&63)
// computes rows {rsub, rsub+4, rsub+8, rsub+12}, column j.
template<int K>
__global__ __launch_bounds__(256) void gemm_hs(const float* __restrict__ X,
                                               const float* __restrict__ W,
                                               const float* __restrict__ dinv,
                                               float* __restrict__ out) {
    __shared__ float Ws[K * HID_];
    __shared__ float Xs[16][K];
    int tid = threadIdx.x;

    for (int i = tid * 4; i < K * HID_; i += 256 * 4)
        *(float4*)&Ws[i] = *(const float4*)&W[i];

    const float* Xb = X + (long)blockIdx.x * 16 * K;
    for (int i = tid * 4; i < 16 * K; i += 256 * 4)
        *(float4*)&Xs[0][i] = *(const float4*)&Xb[i];

    __syncthreads();

    int j = tid & 63;
    int rsub = tid >> 6;
    float acc0 = 0.f, acc1 = 0.f, acc2 = 0.f, acc3 = 0.f;
#pragma unroll 8
    for (int k = 0; k < K; k++) {
        float w = Ws[k * HID_ + j];
        acc0 = fmaf(Xs[rsub + 0][k], w, acc0);
        acc1 = fmaf(Xs[rsub + 4][k], w, acc1);
        acc2 = fmaf(Xs[rsub + 8][k], w, acc2);
        acc3 = fmaf(Xs[rsub + 12][k], w, acc3);
    }
    int base = blockIdx.x * 16;
    float a[4] = {acc0, acc1, acc2, acc3};
#pragma unroll
    for (int rr = 0; rr < 4; rr++) {
        int r = base + rsub + 4 * rr;
        out[(long)r * HID_ + j] = a[rr] * dinv[r];
    }
}

// ---------------- edge scatter: acc[dst][j] += hs[src][j] ----------------
// One wave per group of EPW edges; lane j = feature j.
#define EPW 8
__global__ __launch_bounds__(256) void scatter_feat(const int* __restrict__ idx,
                                                    const float* __restrict__ hs,
                                                    float* __restrict__ acc, int E) {
    int wave = (blockIdx.x * 256 + threadIdx.x) >> 6;
    int j = threadIdx.x & 63;
    int e0 = wave * EPW;
#pragma unroll
    for (int t = 0; t < EPW; t++) {
        int e = e0 + t;
        int s = idx[e];          // src
        int d = idx[E + e];      // dst
        float v = hs[s * HID_ + j];
        atomicAdd(&acc[d * HID_ + j], v);
    }
}

// ---------------- epilogue: y = relu(bn(dinv*(acc+hs) + b)) ----------------
__global__ __launch_bounds__(256) void epilogue_k(const float* __restrict__ acc,
                                                  const float* __restrict__ hs,
                                                  const float* __restrict__ dinv,
                                                  const float* __restrict__ b,
                                                  const float* __restrict__ g,
                                                  const float* __restrict__ beta,
                                                  const float* __restrict__ m,
                                                  const float* __restrict__ v,
                                                  float* __restrict__ y) {
    int t = blockIdx.x * 256 + threadIdx.x;
    int i = t >> 6, j = t & 63;
    float s = g[j] * rsqrtf(v[j] + BN_EPS_);
    float z = dinv[i] * (acc[t] + hs[t]);
    float val = (z + b[j] - m[j]) * s + beta[j];
    y[t] = fmaxf(val, 0.f);
}

// ---------------- layer 3: hs3[i] = dinv[i] * sum_j y2[i][j]*W3[j] ----------------
__global__ __launch_bounds__(256) void gemv3(const float* __restrict__ y2,
                                             const float* __restrict__ W3,
                                             const float* __restrict__ dinv,
                                             float* __restrict__ hs3) {
    int t = blockIdx.x * 256 + threadIdx.x;
    int i = t >> 6, j = t & 63;
    float p = y2[t] * W3[j];
#pragma unroll
    for (int off = 32; off > 0; off >>= 1)
        p += __shfl_down(p, off, 64);
    if (j == 0) hs3[i] = p * dinv[i];
}

__global__ __launch_bounds__(256) void scatter3(const int* __restrict__ idx,
                                                const float* __restrict__ hs3,
                                                float* __restrict__ acc3, int E) {
    int e = blockIdx.x * 256 + threadIdx.x;
    if (e < E) atomicAdd(&acc3[idx[E + e]], hs3[idx[e]]);
}

__global__ __launch_bounds__(256) void final_k(const float* __restrict__ acc3,
                                               const float* __restrict__ hs3,
                                               const float* __restrict__ dinv,
                                               const float* __restrict__ b3,
                                               float* __restrict__ out, int n) {
    int i = blockIdx.x * 256 + threadIdx.x;
    if (i < n) {
        float z = dinv[i] * (acc3[i] + hs3[i]) + b3[0];
        out[i] = 1.f / (1.f + expf(-z));
    }
}

extern "C" void kernel_launch(void* const* d_in, const int* in_sizes, int n_in,
                              void* d_out, int out_size, void* d_ws, size_t ws_size,
                              hipStream_t stream) {
    const int N = N_NODES;
    const int E = E_EDGES;

    const float* x   = (const float*)d_in[0];
    const int*   ei  = (const int*)d_in[1];   // [2, E] int32: row0=src, row1=dst
    const float* W1  = (const float*)d_in[2];
    const float* b1  = (const float*)d_in[3];
    const float* W2  = (const float*)d_in[4];
    const float* b2  = (const float*)d_in[5];
    const float* W3  = (const float*)d_in[6];
    const float* b3  = (const float*)d_in[7];
    const float* g1  = (const float*)d_in[8];
    const float* bt1 = (const float*)d_in[9];
    const float* m1  = (const float*)d_in[10];
    const float* v1  = (const float*)d_in[11];
    const float* g2  = (const float*)d_in[12];
    const float* bt2 = (const float*)d_in[13];
    const float* m2  = (const float*)d_in[14];
    const float* v2  = (const float*)d_in[15];
    float* out = (float*)d_out;

    // workspace layout (floats)
    float* ws    = (float*)d_ws;
    float* dinv  = ws;                 // N
    int*   deg   = (int*)(ws + N);     // N
    float* hs3   = ws + 2L * N;        // N
    float* acc3  = ws + 3L * N;        // N
    float* A     = ws + 4L * N;        // 64*N  (hs buffer)
    float* B     = ws + 4L * N + 64L * N; // 64*N (acc / y buffer)

    // ---- degree + dinv ----
    hipMemsetAsync(deg, 0, (size_t)N * 4, stream);
    deg_kernel<<<E / 256, 256, 0, stream>>>(ei + E, deg, E);
    dinv_kernel<<<(N + 255) / 256, 256, 0, stream>>>(deg, dinv, N);

    // ---- layer 1 ----
    hipMemsetAsync(B, 0, (size_t)N * HID_ * 4, stream);
    gemm_hs<IN_DIM_><<<N / 16, 256, 0, stream>>>(x, W1, dinv, A);
    scatter_feat<<<E / (4 * EPW), 256, 0, stream>>>(ei, A, B, E);
    epilogue_k<<<(N * HID_) / 256, 256, 0, stream>>>(B, A, dinv, b1, g1, bt1, m1, v1, B);

    // ---- layer 2 ----
    gemm_hs<HID_><<<N / 16, 256, 0, stream>>>(B, W2, dinv, A);
    hipMemsetAsync(B, 0, (size_t)N * HID_ * 4, stream);
    scatter_feat<<<E / (4 * EPW), 256, 0, stream>>>(ei, A, B, E);
    epilogue_k<<<(N * HID_) / 256, 256, 0, stream>>>(B, A, dinv, b2, g2, bt2, m2, v2, B);

    // ---- layer 3 ----
    gemv3<<<(N * HID_) / 256, 256, 0, stream>>>(B, W3, dinv, hs3);
    hipMemsetAsync(acc3, 0, (size_t)N * 4, stream);
    scatter3<<<E / 256, 256, 0, stream>>>(ei, hs3, acc3, E);
    final_k<<<(N + 255) / 256, 256, 0, stream>>>(acc3, hs3, dinv, b3, out, N);
}

// Round 2
// 663.943 us; speedup vs baseline: 2.7403x; 2.7403x over previous
//
#include <hip/hip_runtime.h>
#include <math.h>

#define N_NODES 100000
#define E_EDGES 3200000
#define IN_DIM_ 128
#define HID_ 64
#define BN_EPS_ 1e-5f

// ---------------- degree ----------------

__global__ __launch_bounds__(256) void deg_kernel(const int* __restrict__ dst,
                                                  int* __restrict__ deg, int E) {
    int e = blockIdx.x * 256 + threadIdx.x;
    if (e < E) atomicAdd(&deg[dst[e]], 1);
}

__global__ __launch_bounds__(256) void dinv_kernel(const int* __restrict__ deg,
                                                   float* __restrict__ dinv, int n) {
    int i = blockIdx.x * 256 + threadIdx.x;
    if (i < n) dinv[i] = rsqrtf((float)deg[i] + 1.0f);
}

// ---------------- prefix sum (3 kernels): deg -> row_ptr ----------------
// 1024 elements per block, 98 blocks for N=100000.

__global__ __launch_bounds__(256) void block_sums_k(const int* __restrict__ deg,
                                                    int* __restrict__ sums, int n) {
    __shared__ int sh[256];
    int base = blockIdx.x * 1024, t = threadIdx.x;
    int s = 0;
#pragma unroll
    for (int k = 0; k < 4; k++) {
        int i = base + t * 4 + k;
        if (i < n) s += deg[i];
    }
    sh[t] = s;
    __syncthreads();
    for (int off = 128; off > 0; off >>= 1) {
        if (t < off) sh[t] += sh[t + off];
        __syncthreads();
    }
    if (t == 0) sums[blockIdx.x] = sh[0];
}

// single block: exclusive scan of nb (<=128) block sums, in place
__global__ __launch_bounds__(128) void scan_sums_k(int* __restrict__ sums, int nb) {
    __shared__ int sh[128];
    int t = threadIdx.x;
    int orig = (t < nb) ? sums[t] : 0;
    sh[t] = orig;
    __syncthreads();
    for (int off = 1; off < 128; off <<= 1) {
        int u = (t >= off) ? sh[t - off] : 0;
        __syncthreads();
        sh[t] += u;
        __syncthreads();
    }
    if (t < nb) sums[t] = sh[t] - orig;  // exclusive
}

__global__ __launch_bounds__(256) void row_ptr_k(const int* __restrict__ deg,
                                                 const int* __restrict__ block_off,
                                                 int* __restrict__ row_ptr,
                                                 int* __restrict__ cursor,
                                                 int n, int E) {
    __shared__ int sh[256];
    int base = blockIdx.x * 1024, t = threadIdx.x;
    int v[4];
    int s = 0;
#pragma unroll
    for (int k = 0; k < 4; k++) {
        int i = base + t * 4 + k;
        v[k] = (i < n) ? deg[i] : 0;
        s += v[k];
    }
    sh[t] = s;
    __syncthreads();
    int orig = s;
    for (int off = 1; off < 256; off <<= 1) {
        int u = (t >= off) ? sh[t - off] : 0;
        __syncthreads();
        sh[t] += u;
        __syncthreads();
    }
    int ex = sh[t] - orig + block_off[blockIdx.x];
#pragma unroll
    for (int k = 0; k < 4; k++) {
        int i = base + t * 4 + k;
        if (i < n) {
            row_ptr[i] = ex;
            cursor[i] = ex;
            ex += v[k];
        }
    }
    if (blockIdx.x == 0 && t == 0) row_ptr[n] = E;
}

// ---------------- CSR placement ----------------
__global__ __launch_bounds__(256) void place_k(const int* __restrict__ ei,
                                               int* __restrict__ cursor,
                                               int* __restrict__ csr_src, int E) {
    int e = blockIdx.x * 256 + threadIdx.x;
    if (e < E) {
        int s = ei[e];
        int d = ei[E + e];
        int pos = atomicAdd(&cursor[d], 1);
        csr_src[pos] = s;
    }
}

// ---------------- hs = (X @ W) * dinv[row] ----------------
template<int K>
__global__ __launch_bounds__(256) void gemm_hs(const float* __restrict__ X,
                                               const float* __restrict__ W,
                                               const float* __restrict__ dinv,
                                               float* __restrict__ out) {
    __shared__ float Ws[K * HID_];
    __shared__ float Xs[16][K];
    int tid = threadIdx.x;

    for (int i = tid * 4; i < K * HID_; i += 256 * 4)
        *(float4*)&Ws[i] = *(const float4*)&W[i];

    const float* Xb = X + (long)blockIdx.x * 16 * K;
    for (int i = tid * 4; i < 16 * K; i += 256 * 4)
        *(float4*)&Xs[0][i] = *(const float4*)&Xb[i];

    __syncthreads();

    int j = tid & 63;
    int rsub = tid >> 6;
    float acc0 = 0.f, acc1 = 0.f, acc2 = 0.f, acc3 = 0.f;
#pragma unroll 8
    for (int k = 0; k < K; k++) {
        float w = Ws[k * HID_ + j];
        acc0 = fmaf(Xs[rsub + 0][k], w, acc0);
        acc1 = fmaf(Xs[rsub + 4][k], w, acc1);
        acc2 = fmaf(Xs[rsub + 8][k], w, acc2);
        acc3 = fmaf(Xs[rsub + 12][k], w, acc3);
    }
    int base = blockIdx.x * 16;
    float a[4] = {acc0, acc1, acc2, acc3};
#pragma unroll
    for (int rr = 0; rr < 4; rr++) {
        int r = base + rsub + 4 * rr;
        out[(long)r * HID_ + j] = a[rr] * dinv[r];
    }
}

// ---------------- pull-gather + fused BN/ReLU epilogue ----------------
// One wave per node; lane j = feature. y[i,j] = relu(bn(dinv[i]*sum + b))
__global__ __launch_bounds__(256) void gather_feat(const int* __restrict__ row_ptr,
                                                   const int* __restrict__ csr_src,
                                                   const float* __restrict__ hs,
                                                   const float* __restrict__ dinv,
                                                   const float* __restrict__ b,
                                                   const float* __restrict__ g,
                                                   const float* __restrict__ beta,
                                                   const float* __restrict__ m,
                                                   const float* __restrict__ v,
                                                   float* __restrict__ y, int n) {
    int i = (blockIdx.x * 256 + threadIdx.x) >> 6;
    int j = threadIdx.x & 63;
    if (i >= n) return;
    int beg = row_ptr[i], end = row_ptr[i + 1];
    float a0 = hs[(long)i * HID_ + j], a1 = 0.f, a2 = 0.f, a3 = 0.f;
    int k = beg;
    for (; k + 4 <= end; k += 4) {
        int s0 = csr_src[k], s1 = csr_src[k + 1], s2 = csr_src[k + 2], s3 = csr_src[k + 3];
        a0 += hs[(long)s0 * HID_ + j];
        a1 += hs[(long)s1 * HID_ + j];
        a2 += hs[(long)s2 * HID_ + j];
        a3 += hs[(long)s3 * HID_ + j];
    }
    for (; k < end; k++) a0 += hs[(long)csr_src[k] * HID_ + j];
    float acc = (a0 + a1) + (a2 + a3);
    float sc = g[j] * rsqrtf(v[j] + BN_EPS_);
    float z = dinv[i] * acc;
    y[(long)i * HID_ + j] = fmaxf((z + b[j] - m[j]) * sc + beta[j], 0.f);
}

// ---------------- layer 3: hs3[i] = dinv[i] * sum_j y2[i][j]*W3[j] ----------------
__global__ __launch_bounds__(256) void gemv3(const float* __restrict__ y2,
                                             const float* __restrict__ W3,
                                             const float* __restrict__ dinv,
                                             float* __restrict__ hs3) {
    int t = blockIdx.x * 256 + threadIdx.x;
    int i = t >> 6, j = t & 63;
    float p = y2[t] * W3[j];
#pragma unroll
    for (int off = 32; off > 0; off >>= 1)
        p += __shfl_down(p, off, 64);
    if (j == 0) hs3[i] = p * dinv[i];
}

// ---------------- layer-3 pull + sigmoid ----------------
__global__ __launch_bounds__(256) void gather3(const int* __restrict__ row_ptr,
                                               const int* __restrict__ csr_src,
                                               const float* __restrict__ hs3,
                                               const float* __restrict__ dinv,
                                               const float* __restrict__ b3,
                                               float* __restrict__ out, int n) {
    int i = blockIdx.x * 256 + threadIdx.x;
    if (i >= n) return;
    int beg = row_ptr[i], end = row_ptr[i + 1];
    float s0 = hs3[i], s1 = 0.f, s2 = 0.f, s3 = 0.f;
    int k = beg;
    for (; k + 4 <= end; k += 4) {
        s0 += hs3[csr_src[k]];
        s1 += hs3[csr_src[k + 1]];
        s2 += hs3[csr_src[k + 2]];
        s3 += hs3[csr_src[k + 3]];
    }
    for (; k < end; k++) s0 += hs3[csr_src[k]];
    float z = dinv[i] * ((s0 + s1) + (s2 + s3)) + b3[0];
    out[i] = 1.f / (1.f + expf(-z));
}

extern "C" void kernel_launch(void* const* d_in, const int* in_sizes, int n_in,
                              void* d_out, int out_size, void* d_ws, size_t ws_size,
                              hipStream_t stream) {
    const int N = N_NODES;
    const int E = E_EDGES;
    const int NB = (N + 1023) / 1024;  // 98 scan blocks

    const float* x   = (const float*)d_in[0];
    const int*   ei  = (const int*)d_in[1];   // [2, E]: row0=src, row1=dst
    const float* W1  = (const float*)d_in[2];
    const float* b1  = (const float*)d_in[3];
    const float* W2  = (const float*)d_in[4];
    const float* b2  = (const float*)d_in[5];
    const float* W3  = (const float*)d_in[6];
    const float* b3  = (const float*)d_in[7];
    const float* g1  = (const float*)d_in[8];
    const float* bt1 = (const float*)d_in[9];
    const float* m1  = (const float*)d_in[10];
    const float* v1  = (const float*)d_in[11];
    const float* g2  = (const float*)d_in[12];
    const float* bt2 = (const float*)d_in[13];
    const float* m2  = (const float*)d_in[14];
    const float* v2  = (const float*)d_in[15];
    float* out = (float*)d_out;

    // workspace layout (4-byte units)
    float* ws      = (float*)d_ws;
    float* dinv    = ws;                        // N
    int*   deg     = (int*)(ws + (long)N);      // N
    int*   row_ptr = (int*)(ws + 2L * N);       // N+1 (pad 16)
    int*   cursor  = (int*)(ws + 3L * N + 16);  // N
    float* hs3     = ws + 4L * N + 16;          // N
    int*   sums    = (int*)(ws + 5L * N + 16);  // NB (pad 128)
    int*   csr_src = (int*)(ws + 5L * N + 160); // E
    float* A       = ws + 5L * N + 160 + (long)E;          // 64*N
    float* B       = A + 64L * N;                           // 64*N

    // ---- degree / dinv / CSR build ----
    hipMemsetAsync(deg, 0, (size_t)N * 4, stream);
    deg_kernel<<<E / 256, 256, 0, stream>>>(ei + E, deg, E);
    dinv_kernel<<<(N + 255) / 256, 256, 0, stream>>>(deg, dinv, N);
    block_sums_k<<<NB, 256, 0, stream>>>(deg, sums, N);
    scan_sums_k<<<1, 128, 0, stream>>>(sums, NB);
    row_ptr_k<<<NB, 256, 0, stream>>>(deg, sums, row_ptr, cursor, N, E);
    place_k<<<E / 256, 256, 0, stream>>>(ei, cursor, csr_src, E);

    // ---- layer 1 ----
    gemm_hs<IN_DIM_><<<N / 16, 256, 0, stream>>>(x, W1, dinv, A);
    gather_feat<<<(N * 4 + 255) / 256 * 64 / 64, 256, 0, stream>>>(row_ptr, csr_src, A, dinv,
                                                                   b1, g1, bt1, m1, v1, B, N);
    // ---- layer 2 ----
    gemm_hs<HID_><<<N / 16, 256, 0, stream>>>(B, W2, dinv, A);
    gather_feat<<<(N * 4 + 255) / 256 * 64 / 64, 256, 0, stream>>>(row_ptr, csr_src, A, dinv,
                                                                   b2, g2, bt2, m2, v2, B, N);
    // ---- layer 3 ----
    gemv3<<<(N * HID_) / 256, 256, 0, stream>>>(B, W3, dinv, hs3);
    gather3<<<(N + 255) / 256, 256, 0, stream>>>(row_ptr, csr_src, hs3, dinv, b3, out, N);
}

// Round 3
// 603.232 us; speedup vs baseline: 3.0161x; 1.1006x over previous
//
#include <hip/hip_runtime.h>
#include <math.h>

#define N_NODES 100000
#define E_EDGES 3200000
#define IN_DIM_ 128
#define HID_ 64
#define BN_EPS_ 1e-5f

#define PB 200          // edge-chunk blocks
#define CHUNK 16000     // E / PB exactly
#define NBUCK 391       // ceil(N / 256): bucket = dst >> 8
#define SCAN_TOT (NBUCK * PB)

// ---------------- pass A1: per-block bucket histogram ----------------
__global__ __launch_bounds__(256) void passA1_hist(const int* __restrict__ ei,
                                                   int* __restrict__ histPB) {
    __shared__ int hist[NBUCK];
    int t = threadIdx.x, b = blockIdx.x;
    for (int k = t; k < NBUCK; k += 256) hist[k] = 0;
    __syncthreads();
    int e0 = b * CHUNK, e1 = e0 + CHUNK;
    for (int e = e0 + t; e < e1; e += 256) {
        int d = ei[E_EDGES + e];
        atomicAdd(&hist[d >> 8], 1);
    }
    __syncthreads();
    for (int k = t; k < NBUCK; k += 256) histPB[k * PB + b] = hist[k];
}

// ---------------- exclusive scan of histPB (single block, wave shuffles) ----
__global__ __launch_bounds__(1024) void scan_hist(int* __restrict__ histPB,
                                                  int* __restrict__ bucket_base,
                                                  int* __restrict__ row_ptr) {
    __shared__ int wsum[16];
    __shared__ int running_sh;
    int t = threadIdx.x, lane = t & 63, wv = t >> 6;
    if (t == 0) running_sh = 0;
    __syncthreads();
    for (int base = 0; base < SCAN_TOT; base += 1024) {
        int i = base + t;
        int v = (i < SCAN_TOT) ? histPB[i] : 0;
        int s = v;
#pragma unroll
        for (int off = 1; off < 64; off <<= 1) {
            int u = __shfl_up(s, off, 64);
            if (lane >= off) s += u;
        }
        if (lane == 63) wsum[wv] = s;
        __syncthreads();
        if (wv == 0) {
            int ws2 = (lane < 16) ? wsum[lane] : 0;
#pragma unroll
            for (int off = 1; off < 16; off <<= 1) {
                int u = __shfl_up(ws2, off, 64);
                if (lane >= off) ws2 += u;
            }
            if (lane < 16) wsum[lane] = ws2;
        }
        __syncthreads();
        int run = running_sh;
        int wbase = (wv == 0) ? 0 : wsum[wv - 1];
        if (i < SCAN_TOT) histPB[i] = run + wbase + s - v;
        __syncthreads();
        if (t == 0) running_sh = run + wsum[15];
        __syncthreads();
    }
    for (int i = t; i < NBUCK; i += 1024) bucket_base[i] = histPB[i * PB];
    if (t == 0) {
        bucket_base[NBUCK] = E_EDGES;
        row_ptr[N_NODES] = E_EDGES;
    }
}

// ---------------- pass A2: bucket-scatter packed edges ----------------
__global__ __launch_bounds__(256) void passA2_scatter(const int* __restrict__ ei,
                                                      const int* __restrict__ histPB,
                                                      int* __restrict__ ebuf) {
    __shared__ int cur[NBUCK];
    int t = threadIdx.x, b = blockIdx.x;
    for (int k = t; k < NBUCK; k += 256) cur[k] = histPB[k * PB + b];
    __syncthreads();
    int e0 = b * CHUNK, e1 = e0 + CHUNK;
    for (int e = e0 + t; e < e1; e += 256) {
        int s = ei[e];
        int d = ei[E_EDGES + e];
        int bk = d >> 8;
        int pos = atomicAdd(&cur[bk], 1);
        ebuf[pos] = s | ((d & 255) << 17);
    }
}

// ---------------- pass B: per-bucket place + row_ptr + dinv ----------------
__global__ __launch_bounds__(256) void passB_place(const int* __restrict__ ebuf,
                                                   const int* __restrict__ bucket_base,
                                                   int* __restrict__ row_ptr,
                                                   int* __restrict__ csr_src,
                                                   float* __restrict__ dinv) {
    __shared__ int hist[256];
    __shared__ int wsum[4];
    int b = blockIdx.x, t = threadIdx.x, lane = t & 63, wv = t >> 6;
    int base = bucket_base[b], end = bucket_base[b + 1];
    hist[t] = 0;
    __syncthreads();
    for (int k = base + t; k < end; k += 256)
        atomicAdd(&hist[ebuf[k] >> 17], 1);
    __syncthreads();
    int v = hist[t];
    int s = v;
#pragma unroll
    for (int off = 1; off < 64; off <<= 1) {
        int u = __shfl_up(s, off, 64);
        if (lane >= off) s += u;
    }
    if (lane == 63) wsum[wv] = s;
    __syncthreads();
    int wbase = 0;
    for (int w = 0; w < wv; w++) wbase += wsum[w];
    int excl = wbase + s - v;
    int node = b * 256 + t;
    if (node < N_NODES) {
        row_ptr[node] = base + excl;
        dinv[node] = rsqrtf((float)v + 1.0f);
    }
    __syncthreads();
    hist[t] = excl;  // reuse as cursor
    __syncthreads();
    for (int k = base + t; k < end; k += 256) {
        int pv = ebuf[k];
        int pos = atomicAdd(&hist[pv >> 17], 1);
        csr_src[base + pos] = pv & 0x1FFFF;
    }
}

// ---------------- hs = (X @ W) * dinv[row] ----------------
template<int K>
__global__ __launch_bounds__(256) void gemm_hs(const float* __restrict__ X,
                                               const float* __restrict__ W,
                                               const float* __restrict__ dinv,
                                               float* __restrict__ out) {
    __shared__ float Ws[K * HID_];
    __shared__ float Xs[16][K];
    int tid = threadIdx.x;

    for (int i = tid * 4; i < K * HID_; i += 256 * 4)
        *(float4*)&Ws[i] = *(const float4*)&W[i];

    const float* Xb = X + (long)blockIdx.x * 16 * K;
    for (int i = tid * 4; i < 16 * K; i += 256 * 4)
        *(float4*)&Xs[0][i] = *(const float4*)&Xb[i];

    __syncthreads();

    int j = tid & 63;
    int rsub = tid >> 6;
    float acc0 = 0.f, acc1 = 0.f, acc2 = 0.f, acc3 = 0.f;
#pragma unroll 8
    for (int k = 0; k < K; k++) {
        float w = Ws[k * HID_ + j];
        acc0 = fmaf(Xs[rsub + 0][k], w, acc0);
        acc1 = fmaf(Xs[rsub + 4][k], w, acc1);
        acc2 = fmaf(Xs[rsub + 8][k], w, acc2);
        acc3 = fmaf(Xs[rsub + 12][k], w, acc3);
    }
    int base = blockIdx.x * 16;
    float a[4] = {acc0, acc1, acc2, acc3};
#pragma unroll
    for (int rr = 0; rr < 4; rr++) {
        int r = base + rsub + 4 * rr;
        out[(long)r * HID_ + j] = a[rr] * dinv[r];
    }
}

// ---------------- pull-gather + fused BN/ReLU ----------------
// One wave per node; lane j = feature.
__global__ __launch_bounds__(256) void gather_feat(const int* __restrict__ row_ptr,
                                                   const int* __restrict__ csr_src,
                                                   const float* __restrict__ hs,
                                                   const float* __restrict__ dinv,
                                                   const float* __restrict__ b,
                                                   const float* __restrict__ g,
                                                   const float* __restrict__ beta,
                                                   const float* __restrict__ m,
                                                   const float* __restrict__ v,
                                                   float* __restrict__ y, int n) {
    int i = (blockIdx.x * 256 + threadIdx.x) >> 6;
    int j = threadIdx.x & 63;
    if (i >= n) return;
    int beg = row_ptr[i], end = row_ptr[i + 1];
    float a0 = hs[(long)i * HID_ + j], a1 = 0.f, a2 = 0.f, a3 = 0.f;
    int k = beg;
    for (; k + 4 <= end; k += 4) {
        int s0 = csr_src[k], s1 = csr_src[k + 1], s2 = csr_src[k + 2], s3 = csr_src[k + 3];
        a0 += hs[(long)s0 * HID_ + j];
        a1 += hs[(long)s1 * HID_ + j];
        a2 += hs[(long)s2 * HID_ + j];
        a3 += hs[(long)s3 * HID_ + j];
    }
    for (; k < end; k++) a0 += hs[(long)csr_src[k] * HID_ + j];
    float acc = (a0 + a1) + (a2 + a3);
    float sc = g[j] * rsqrtf(v[j] + BN_EPS_);
    float z = dinv[i] * acc;
    y[(long)i * HID_ + j] = fmaxf((z + b[j] - m[j]) * sc + beta[j], 0.f);
}

// ---------------- layer 3 ----------------
__global__ __launch_bounds__(256) void gemv3(const float* __restrict__ y2,
                                             const float* __restrict__ W3,
                                             const float* __restrict__ dinv,
                                             float* __restrict__ hs3) {
    int t = blockIdx.x * 256 + threadIdx.x;
    int i = t >> 6, j = t & 63;
    float p = y2[t] * W3[j];
#pragma unroll
    for (int off = 32; off > 0; off >>= 1)
        p += __shfl_down(p, off, 64);
    if (j == 0) hs3[i] = p * dinv[i];
}

__global__ __launch_bounds__(256) void gather3(const int* __restrict__ row_ptr,
                                               const int* __restrict__ csr_src,
                                               const float* __restrict__ hs3,
                                               const float* __restrict__ dinv,
                                               const float* __restrict__ b3,
                                               float* __restrict__ out, int n) {
    int i = blockIdx.x * 256 + threadIdx.x;
    if (i >= n) return;
    int beg = row_ptr[i], end = row_ptr[i + 1];
    float s0 = hs3[i], s1 = 0.f, s2 = 0.f, s3 = 0.f;
    int k = beg;
    for (; k + 4 <= end; k += 4) {
        s0 += hs3[csr_src[k]];
        s1 += hs3[csr_src[k + 1]];
        s2 += hs3[csr_src[k + 2]];
        s3 += hs3[csr_src[k + 3]];
    }
    for (; k < end; k++) s0 += hs3[csr_src[k]];
    float z = dinv[i] * ((s0 + s1) + (s2 + s3)) + b3[0];
    out[i] = 1.f / (1.f + expf(-z));
}

extern "C" void kernel_launch(void* const* d_in, const int* in_sizes, int n_in,
                              void* d_out, int out_size, void* d_ws, size_t ws_size,
                              hipStream_t stream) {
    const int N = N_NODES;
    const int E = E_EDGES;

    const float* x   = (const float*)d_in[0];
    const int*   ei  = (const int*)d_in[1];   // [2, E]: row0=src, row1=dst
    const float* W1  = (const float*)d_in[2];
    const float* b1  = (const float*)d_in[3];
    const float* W2  = (const float*)d_in[4];
    const float* b2  = (const float*)d_in[5];
    const float* W3  = (const float*)d_in[6];
    const float* b3  = (const float*)d_in[7];
    const float* g1  = (const float*)d_in[8];
    const float* bt1 = (const float*)d_in[9];
    const float* m1  = (const float*)d_in[10];
    const float* v1  = (const float*)d_in[11];
    const float* g2  = (const float*)d_in[12];
    const float* bt2 = (const float*)d_in[13];
    const float* m2  = (const float*)d_in[14];
    const float* v2  = (const float*)d_in[15];
    float* out = (float*)d_out;

    // workspace layout (4-byte units)
    float* ws          = (float*)d_ws;
    float* dinv        = ws;                              // N
    float* hs3         = ws + (long)N;                    // N
    int*   row_ptr     = (int*)(ws + 2L * N);             // N+1 (pad 16)
    int*   histPB      = (int*)(ws + 3L * N + 16);        // NBUCK*PB = 78200
    int*   bucket_base = histPB + SCAN_TOT;               // NBUCK+1 (pad to 408)
    int*   csr_src     = bucket_base + 408;               // E
    float* A           = (float*)(csr_src + (long)E);     // 64*N  (hs buffer)
    float* B           = A + 64L * N;                     // 64*N
    int*   ebuf        = (int*)A;                         // E ints, aliases A

    // ---- CSR build (bucketed counting sort, no global atomics) ----
    passA1_hist<<<PB, 256, 0, stream>>>(ei, histPB);
    scan_hist<<<1, 1024, 0, stream>>>(histPB, bucket_base, row_ptr);
    passA2_scatter<<<PB, 256, 0, stream>>>(ei, histPB, ebuf);
    passB_place<<<NBUCK, 256, 0, stream>>>(ebuf, bucket_base, row_ptr, csr_src, dinv);

    // ---- layer 1 ----
    gemm_hs<IN_DIM_><<<N / 16, 256, 0, stream>>>(x, W1, dinv, A);
    gather_feat<<<N / 4, 256, 0, stream>>>(row_ptr, csr_src, A, dinv,
                                           b1, g1, bt1, m1, v1, B, N);
    // ---- layer 2 ----
    gemm_hs<HID_><<<N / 16, 256, 0, stream>>>(B, W2, dinv, A);
    gather_feat<<<N / 4, 256, 0, stream>>>(row_ptr, csr_src, A, dinv,
                                           b2, g2, bt2, m2, v2, B, N);
    // ---- layer 3 ----
    gemv3<<<(N * HID_) / 256, 256, 0, stream>>>(B, W3, dinv, hs3);
    gather3<<<(N + 255) / 256, 256, 0, stream>>>(row_ptr, csr_src, hs3, dinv, b3, out, N);
}

// Round 4
// 473.924 us; speedup vs baseline: 3.8391x; 1.2728x over previous
//
#include <hip/hip_runtime.h>
#include <math.h>

#define N_NODES 100000
#define E_EDGES 3200000
#define IN_DIM_ 128
#define HID_ 64
#define BN_EPS_ 1e-5f

#define PB 200          // edge-chunk blocks
#define CHUNK 16000     // E / PB exactly
#define NBUCK 391       // ceil(N / 256): bucket = dst >> 8

typedef __attribute__((ext_vector_type(8))) short short8;
typedef __attribute__((ext_vector_type(4))) float f32x4;

__device__ inline ushort f2bf(float f) {
    union { float f; unsigned u; } c; c.f = f;
    unsigned r = c.u + 0x7fff + ((c.u >> 16) & 1);   // RNE
    return (ushort)(r >> 16);
}

// ---------------- pass A1: per-block bucket histogram ----------------
__global__ __launch_bounds__(256) void passA1_hist(const int* __restrict__ ei,
                                                   int* __restrict__ histPB) {
    __shared__ int hist[NBUCK];
    int t = threadIdx.x, b = blockIdx.x;
    for (int k = t; k < NBUCK; k += 256) hist[k] = 0;
    __syncthreads();
    int e0 = b * CHUNK, e1 = e0 + CHUNK;
    for (int e = e0 + t; e < e1; e += 256) {
        int d = ei[E_EDGES + e];
        atomicAdd(&hist[d >> 8], 1);
    }
    __syncthreads();
    for (int k = t; k < NBUCK; k += 256) histPB[k * PB + b] = hist[k];
}

// ---------------- per-bucket row scan: histPB row -> exclusive, total ------
__global__ __launch_bounds__(256) void scan_rows(int* __restrict__ histPB,
                                                 int* __restrict__ bucket_tot) {
    __shared__ int wsum[4];
    int k = blockIdx.x, t = threadIdx.x, lane = t & 63, wv = t >> 6;
    int v = (t < PB) ? histPB[k * PB + t] : 0;
    int s = v;
#pragma unroll
    for (int off = 1; off < 64; off <<= 1) {
        int u = __shfl_up(s, off, 64);
        if (lane >= off) s += u;
    }
    if (lane == 63) wsum[wv] = s;
    __syncthreads();
    int wbase = 0;
    for (int w = 0; w < wv; w++) wbase += wsum[w];
    if (t < PB) histPB[k * PB + t] = wbase + s - v;
    if (t == 255) bucket_tot[k] = wbase + s;
}

// ---------------- scan bucket totals -> bucket_base ----------------
__global__ __launch_bounds__(512) void scan_totals(const int* __restrict__ bucket_tot,
                                                   int* __restrict__ bucket_base,
                                                   int* __restrict__ row_ptr) {
    __shared__ int wsum[8];
    int t = threadIdx.x, lane = t & 63, wv = t >> 6;
    int v = (t < NBUCK) ? bucket_tot[t] : 0;
    int s = v;
#pragma unroll
    for (int off = 1; off < 64; off <<= 1) {
        int u = __shfl_up(s, off, 64);
        if (lane >= off) s += u;
    }
    if (lane == 63) wsum[wv] = s;
    __syncthreads();
    int wbase = 0;
    for (int w = 0; w < wv; w++) wbase += wsum[w];
    if (t < NBUCK) bucket_base[t] = wbase + s - v;
    if (t == 0) {
        bucket_base[NBUCK] = E_EDGES;
        row_ptr[N_NODES] = E_EDGES;
    }
}

// ---------------- pass A2: bucket-scatter packed edges ----------------
__global__ __launch_bounds__(256) void passA2_scatter(const int* __restrict__ ei,
                                                      const int* __restrict__ histPB,
                                                      const int* __restrict__ bucket_base,
                                                      int* __restrict__ ebuf) {
    __shared__ int cur[NBUCK];
    int t = threadIdx.x, b = blockIdx.x;
    for (int k = t; k < NBUCK; k += 256) cur[k] = bucket_base[k] + histPB[k * PB + b];
    __syncthreads();
    int e0 = b * CHUNK, e1 = e0 + CHUNK;
    for (int e = e0 + t; e < e1; e += 256) {
        int s = ei[e];
        int d = ei[E_EDGES + e];
        int bk = d >> 8;
        int pos = atomicAdd(&cur[bk], 1);
        ebuf[pos] = s | ((d & 255) << 17);
    }
}

// ---------------- pass B: per-bucket place + row_ptr + dinv ----------------
__global__ __launch_bounds__(256) void passB_place(const int* __restrict__ ebuf,
                                                   const int* __restrict__ bucket_base,
                                                   int* __restrict__ row_ptr,
                                                   int* __restrict__ csr_src,
                                                   float* __restrict__ dinv) {
    __shared__ int hist[256];
    __shared__ int wsum[4];
    int b = blockIdx.x, t = threadIdx.x, lane = t & 63, wv = t >> 6;
    int base = bucket_base[b], end = bucket_base[b + 1];
    hist[t] = 0;
    __syncthreads();
    for (int k = base + t; k < end; k += 256)
        atomicAdd(&hist[ebuf[k] >> 17], 1);
    __syncthreads();
    int v = hist[t];
    int s = v;
#pragma unroll
    for (int off = 1; off < 64; off <<= 1) {
        int u = __shfl_up(s, off, 64);
        if (lane >= off) s += u;
    }
    if (lane == 63) wsum[wv] = s;
    __syncthreads();
    int wbase = 0;
    for (int w = 0; w < wv; w++) wbase += wsum[w];
    int excl = wbase + s - v;
    int node = b * 256 + t;
    if (node < N_NODES) {
        row_ptr[node] = base + excl;
        dinv[node] = rsqrtf((float)v + 1.0f);
    }
    __syncthreads();
    hist[t] = excl;  // reuse as cursor
    __syncthreads();
    for (int k = base + t; k < end; k += 256) {
        int pv = ebuf[k];
        int pos = atomicAdd(&hist[pv >> 17], 1);
        csr_src[base + pos] = pv & 0x1FFFF;
    }
}

// ---------------- MFMA GEMM: hs(bf16) = (X @ W) * dinv[row] ----------------
// 64 rows/block, 4 waves; wave w computes rows [16w,16w+16) x 64 cols.
template<int K>
__global__ __launch_bounds__(256) void gemm_bf16(const float* __restrict__ X,
                                                 const float* __restrict__ W,   // [K][64]
                                                 const float* __restrict__ dinv,
                                                 ushort* __restrict__ hs) {     // [N][64] bf16
    constexpr int KP = K + 8;            // padded stride (bf16 units) -> 2-way banks only
    constexpr int K4 = K / 4;
    __shared__ ushort A_lds[64][KP];
    __shared__ ushort Wt_lds[64][KP];
    int t = threadIdx.x;
    long row0 = (long)blockIdx.x * 64;

    // stage W transposed (bf16): Wt[n][k] = W[k][n]
    for (int i = t; i < K * 64; i += 256) {
        int k = i >> 6, n = i & 63;
        Wt_lds[n][k] = f2bf(W[i]);
    }
    // stage X tile (bf16), row-guarded
    for (int i = t; i < 64 * K4; i += 256) {
        int r = i / K4, c = i % K4;
        float4 val = make_float4(0.f, 0.f, 0.f, 0.f);
        long row = row0 + r;
        if (row < N_NODES) val = ((const float4*)X)[row * K4 + c];
        int cb = c * 4;
        A_lds[r][cb + 0] = f2bf(val.x);
        A_lds[r][cb + 1] = f2bf(val.y);
        A_lds[r][cb + 2] = f2bf(val.z);
        A_lds[r][cb + 3] = f2bf(val.w);
    }
    __syncthreads();

    int w = t >> 6, l = t & 63;
    int m = l & 15, quad = l >> 4;
    f32x4 acc[4];
#pragma unroll
    for (int c = 0; c < 4; c++) acc[c] = (f32x4){0.f, 0.f, 0.f, 0.f};

#pragma unroll
    for (int ch = 0; ch < K / 32; ch++) {
        short8 a = *(const short8*)&A_lds[16 * w + m][32 * ch + 8 * quad];
#pragma unroll
        for (int c = 0; c < 4; c++) {
            short8 b = *(const short8*)&Wt_lds[16 * c + m][32 * ch + 8 * quad];
            acc[c] = __builtin_amdgcn_mfma_f32_16x16x32_bf16(a, b, acc[c], 0, 0, 0);
        }
    }

#pragma unroll
    for (int r = 0; r < 4; r++) {
        long node = row0 + 16 * w + quad * 4 + r;
        if (node < N_NODES) {
            float dv = dinv[node];
#pragma unroll
            for (int c = 0; c < 4; c++)
                hs[node * 64 + 16 * c + m] = f2bf(acc[c][r] * dv);
        }
    }
}

// ---------------- pull-gather (bf16 hs) + fused BN/ReLU ----------------
// One wave per node, 2 edges in flight: half = lane>>5 picks the edge,
// u = lane&31 picks the uint (2 bf16 features) within the 128 B row.
__global__ __launch_bounds__(256) void gather_feat(const int* __restrict__ row_ptr,
                                                   const int* __restrict__ csr_src,
                                                   const ushort* __restrict__ hs,
                                                   const float* __restrict__ dinv,
                                                   const float* __restrict__ b,
                                                   const float* __restrict__ g,
                                                   const float* __restrict__ beta,
                                                   const float* __restrict__ m,
                                                   const float* __restrict__ v,
                                                   float* __restrict__ y, int n) {
    int i = (blockIdx.x * 256 + threadIdx.x) >> 6;
    if (i >= n) return;
    int l = threadIdx.x & 63;
    int half = l >> 5, u = l & 31;
    const unsigned* H = (const unsigned*)hs;
    int beg = row_ptr[i], end = row_ptr[i + 1];
    float a0 = 0.f, a1 = 0.f;
    int k = beg + half;
    for (; k + 2 < end; k += 4) {
        int s0 = csr_src[k], s1 = csr_src[k + 2];
        unsigned p0 = H[s0 * 32 + u], p1 = H[s1 * 32 + u];
        union { unsigned u; float f; } c0, c1, c2, c3;
        c0.u = p0 << 16; c1.u = p0 & 0xffff0000u;
        c2.u = p1 << 16; c3.u = p1 & 0xffff0000u;
        a0 += c0.f + c2.f;
        a1 += c1.f + c3.f;
    }
    for (; k < end; k += 2) {
        unsigned p = H[csr_src[k] * 32 + u];
        union { unsigned u; float f; } cl, ch;
        cl.u = p << 16; ch.u = p & 0xffff0000u;
        a0 += cl.f; a1 += ch.f;
    }
    a0 += __shfl_xor(a0, 32, 64);
    a1 += __shfl_xor(a1, 32, 64);
    // self-loop term
    unsigned ps = H[(long)i * 32 + u];
    union { unsigned u; float f; } sl, sh;
    sl.u = ps << 16; sh.u = ps & 0xffff0000u;
    a0 += sl.f; a1 += sh.f;

    float2 bb = ((const float2*)b)[u];
    float2 gg = ((const float2*)g)[u];
    float2 be = ((const float2*)beta)[u];
    float2 mm = ((const float2*)m)[u];
    float2 vv = ((const float2*)v)[u];
    float di = dinv[i];
    float s0 = gg.x * rsqrtf(vv.x + BN_EPS_);
    float s1 = gg.y * rsqrtf(vv.y + BN_EPS_);
    float o0 = fmaxf((di * a0 + bb.x - mm.x) * s0 + be.x, 0.f);
    float o1 = fmaxf((di * a1 + bb.y - mm.y) * s1 + be.y, 0.f);
    if (half == 0) ((float2*)y)[(long)i * 32 + u] = make_float2(o0, o1);
}

// ---------------- layer 3 ----------------
__global__ __launch_bounds__(256) void gemv3(const float* __restrict__ y2,
                                             const float* __restrict__ W3,
                                             const float* __restrict__ dinv,
                                             float* __restrict__ hs3) {
    int t = blockIdx.x * 256 + threadIdx.x;
    int i = t >> 6, j = t & 63;
    float p = y2[t] * W3[j];
#pragma unroll
    for (int off = 32; off > 0; off >>= 1)
        p += __shfl_down(p, off, 64);
    if (j == 0) hs3[i] = p * dinv[i];
}

__global__ __launch_bounds__(256) void gather3(const int* __restrict__ row_ptr,
                                               const int* __restrict__ csr_src,
                                               const float* __restrict__ hs3,
                                               const float* __restrict__ dinv,
                                               const float* __restrict__ b3,
                                               float* __restrict__ out, int n) {
    int i = blockIdx.x * 256 + threadIdx.x;
    if (i >= n) return;
    int beg = row_ptr[i], end = row_ptr[i + 1];
    float s0 = hs3[i], s1 = 0.f, s2 = 0.f, s3 = 0.f;
    int k = beg;
    for (; k + 4 <= end; k += 4) {
        s0 += hs3[csr_src[k]];
        s1 += hs3[csr_src[k + 1]];
        s2 += hs3[csr_src[k + 2]];
        s3 += hs3[csr_src[k + 3]];
    }
    for (; k < end; k++) s0 += hs3[csr_src[k]];
    float z = dinv[i] * ((s0 + s1) + (s2 + s3)) + b3[0];
    out[i] = 1.f / (1.f + expf(-z));
}

extern "C" void kernel_launch(void* const* d_in, const int* in_sizes, int n_in,
                              void* d_out, int out_size, void* d_ws, size_t ws_size,
                              hipStream_t stream) {
    const int N = N_NODES;
    const int E = E_EDGES;

    const float* x   = (const float*)d_in[0];
    const int*   ei  = (const int*)d_in[1];   // [2, E]: row0=src, row1=dst
    const float* W1  = (const float*)d_in[2];
    const float* b1  = (const float*)d_in[3];
    const float* W2  = (const float*)d_in[4];
    const float* b2  = (const float*)d_in[5];
    const float* W3  = (const float*)d_in[6];
    const float* b3  = (const float*)d_in[7];
    const float* g1  = (const float*)d_in[8];
    const float* bt1 = (const float*)d_in[9];
    const float* m1  = (const float*)d_in[10];
    const float* v1  = (const float*)d_in[11];
    const float* g2  = (const float*)d_in[12];
    const float* bt2 = (const float*)d_in[13];
    const float* m2  = (const float*)d_in[14];
    const float* v2  = (const float*)d_in[15];
    float* out = (float*)d_out;

    // workspace layout (4-byte units)
    int*   wsi         = (int*)d_ws;
    float* dinv        = (float*)wsi;                 // N
    float* hs3         = (float*)(wsi + (long)N);     // N
    int*   row_ptr     = wsi + 2L * N;                // N+1 (pad 16)
    int*   histPB      = wsi + 3L * N + 16;           // NBUCK*PB = 78200
    int*   bucket_tot  = histPB + NBUCK * PB;         // NBUCK (pad 400)
    int*   bucket_base = bucket_tot + 400;            // NBUCK+1 (pad 400)
    int*   csr_src     = bucket_base + 400;           // E
    ushort* hsb        = (ushort*)(csr_src + (long)E);// N*64 bf16 = 32N ints
    float* B           = (float*)(csr_src + (long)E + 32L * N);  // 64N floats
    int*   ebuf        = (int*)hsb;                   // E ints, aliases hsb

    // ---- CSR build (bucketed counting sort, no global atomics) ----
    passA1_hist<<<PB, 256, 0, stream>>>(ei, histPB);
    scan_rows<<<NBUCK, 256, 0, stream>>>(histPB, bucket_tot);
    scan_totals<<<1, 512, 0, stream>>>(bucket_tot, bucket_base, row_ptr);
    passA2_scatter<<<PB, 256, 0, stream>>>(ei, histPB, bucket_base, ebuf);
    passB_place<<<NBUCK, 256, 0, stream>>>(ebuf, bucket_base, row_ptr, csr_src, dinv);

    // ---- layer 1 ----
    gemm_bf16<IN_DIM_><<<(N + 63) / 64, 256, 0, stream>>>(x, W1, dinv, hsb);
    gather_feat<<<N / 4, 256, 0, stream>>>(row_ptr, csr_src, hsb, dinv,
                                           b1, g1, bt1, m1, v1, B, N);
    // ---- layer 2 ----
    gemm_bf16<HID_><<<(N + 63) / 64, 256, 0, stream>>>(B, W2, dinv, hsb);
    gather_feat<<<N / 4, 256, 0, stream>>>(row_ptr, csr_src, hsb, dinv,
                                           b2, g2, bt2, m2, v2, B, N);
    // ---- layer 3 ----
    gemv3<<<(N * HID_) / 256, 256, 0, stream>>>(B, W3, dinv, hs3);
    gather3<<<(N + 255) / 256, 256, 0, stream>>>(row_ptr, csr_src, hs3, dinv, b3, out, N);
}

// Round 5
// 435.050 us; speedup vs baseline: 4.1821x; 1.0894x over previous
//
#include <hip/hip_runtime.h>
#include <math.h>

#define N_NODES 100000
#define E_EDGES 3200000
#define IN_DIM_ 128
#define HID_ 64
#define BN_EPS_ 1e-5f

#define PB 200          // edge-chunk blocks
#define CHUNK 16000     // E / PB exactly
#define NBUCK 391       // ceil(N / 256): bucket = dst >> 8

typedef __attribute__((ext_vector_type(8))) short short8;
typedef __attribute__((ext_vector_type(4))) float f32x4;

__device__ inline ushort f2bf(float f) {
    union { float f; unsigned u; } c; c.f = f;
    unsigned r = c.u + 0x7fff + ((c.u >> 16) & 1);   // RNE
    return (ushort)(r >> 16);
}
__device__ inline float bf_lo(unsigned p) { union { unsigned u; float f; } c; c.u = p << 16; return c.f; }
__device__ inline float bf_hi(unsigned p) { union { unsigned u; float f; } c; c.u = p & 0xffff0000u; return c.f; }

// ---------------- pass A1: per-block bucket histogram ----------------
__global__ __launch_bounds__(256) void passA1_hist(const int* __restrict__ ei,
                                                   int* __restrict__ histPB) {
    __shared__ int hist[NBUCK];
    int t = threadIdx.x, b = blockIdx.x;
    for (int k = t; k < NBUCK; k += 256) hist[k] = 0;
    __syncthreads();
    int e0 = b * CHUNK, e1 = e0 + CHUNK;
    for (int e = e0 + t; e < e1; e += 256) {
        int d = ei[E_EDGES + e];
        atomicAdd(&hist[d >> 8], 1);
    }
    __syncthreads();
    for (int k = t; k < NBUCK; k += 256) histPB[k * PB + b] = hist[k];
}

// ---------------- per-bucket row scan ----------------
__global__ __launch_bounds__(256) void scan_rows(int* __restrict__ histPB,
                                                 int* __restrict__ bucket_tot) {
    __shared__ int wsum[4];
    int k = blockIdx.x, t = threadIdx.x, lane = t & 63, wv = t >> 6;
    int v = (t < PB) ? histPB[k * PB + t] : 0;
    int s = v;
#pragma unroll
    for (int off = 1; off < 64; off <<= 1) {
        int u = __shfl_up(s, off, 64);
        if (lane >= off) s += u;
    }
    if (lane == 63) wsum[wv] = s;
    __syncthreads();
    int wbase = 0;
    for (int w = 0; w < wv; w++) wbase += wsum[w];
    if (t < PB) histPB[k * PB + t] = wbase + s - v;
    if (t == 255) bucket_tot[k] = wbase + s;
}

// ---------------- scan bucket totals -> bucket_base ----------------
__global__ __launch_bounds__(512) void scan_totals(const int* __restrict__ bucket_tot,
                                                   int* __restrict__ bucket_base,
                                                   int* __restrict__ row_ptr) {
    __shared__ int wsum[8];
    int t = threadIdx.x, lane = t & 63, wv = t >> 6;
    int v = (t < NBUCK) ? bucket_tot[t] : 0;
    int s = v;
#pragma unroll
    for (int off = 1; off < 64; off <<= 1) {
        int u = __shfl_up(s, off, 64);
        if (lane >= off) s += u;
    }
    if (lane == 63) wsum[wv] = s;
    __syncthreads();
    int wbase = 0;
    for (int w = 0; w < wv; w++) wbase += wsum[w];
    if (t < NBUCK) bucket_base[t] = wbase + s - v;
    if (t == 0) {
        bucket_base[NBUCK] = E_EDGES;
        row_ptr[N_NODES] = E_EDGES;
    }
}

// ---------------- pass A2: bucket-scatter packed edges ----------------
__global__ __launch_bounds__(256) void passA2_scatter(const int* __restrict__ ei,
                                                      const int* __restrict__ histPB,
                                                      const int* __restrict__ bucket_base,
                                                      int* __restrict__ ebuf) {
    __shared__ int cur[NBUCK];
    int t = threadIdx.x, b = blockIdx.x;
    for (int k = t; k < NBUCK; k += 256) cur[k] = bucket_base[k] + histPB[k * PB + b];
    __syncthreads();
    int e0 = b * CHUNK, e1 = e0 + CHUNK;
    for (int e = e0 + t; e < e1; e += 256) {
        int s = ei[e];
        int d = ei[E_EDGES + e];
        int bk = d >> 8;
        int pos = atomicAdd(&cur[bk], 1);
        ebuf[pos] = s | ((d & 255) << 17);
    }
}

// ---------------- pass B: per-bucket place + row_ptr + dinv ----------------
__global__ __launch_bounds__(256) void passB_place(const int* __restrict__ ebuf,
                                                   const int* __restrict__ bucket_base,
                                                   int* __restrict__ row_ptr,
                                                   int* __restrict__ csr_src,
                                                   float* __restrict__ dinv) {
    __shared__ int hist[256];
    __shared__ int wsum[4];
    int b = blockIdx.x, t = threadIdx.x, lane = t & 63, wv = t >> 6;
    int base = bucket_base[b], end = bucket_base[b + 1];
    hist[t] = 0;
    __syncthreads();
    for (int k = base + t; k < end; k += 256)
        atomicAdd(&hist[ebuf[k] >> 17], 1);
    __syncthreads();
    int v = hist[t];
    int s = v;
#pragma unroll
    for (int off = 1; off < 64; off <<= 1) {
        int u = __shfl_up(s, off, 64);
        if (lane >= off) s += u;
    }
    if (lane == 63) wsum[wv] = s;
    __syncthreads();
    int wbase = 0;
    for (int w = 0; w < wv; w++) wbase += wsum[w];
    int excl = wbase + s - v;
    int node = b * 256 + t;
    if (node < N_NODES) {
        row_ptr[node] = base + excl;
        dinv[node] = rsqrtf((float)v + 1.0f);
    }
    __syncthreads();
    hist[t] = excl;  // reuse as cursor
    __syncthreads();
    for (int k = base + t; k < end; k += 256) {
        int pv = ebuf[k];
        int pos = atomicAdd(&hist[pv >> 17], 1);
        csr_src[base + pos] = pv & 0x1FFFF;
    }
}

// ---------------- MFMA GEMM: hs(bf16) = (X @ W) * dinv[row] ----------------
// 64 rows/block, 4 waves; wave w computes rows [16w,16w+16) x 64 cols.
// BF16IN: X rows are 64 bf16 (packed uints); else f32.
template<int K, bool BF16IN>
__global__ __launch_bounds__(256) void gemm_bf16(const void* __restrict__ Xv,
                                                 const float* __restrict__ W,   // [K][64]
                                                 const float* __restrict__ dinv,
                                                 ushort* __restrict__ hs) {     // [N][64] bf16
    constexpr int KP = K + 8;            // padded stride (bf16 units)
    __shared__ ushort A_lds[64][KP];
    __shared__ ushort Wt_lds[64][KP];
    int t = threadIdx.x;
    long row0 = (long)blockIdx.x * 64;

    // stage W transposed (bf16): Wt[n][k] = W[k][n]; float4 reads
    for (int i = t; i < K * 16; i += 256) {
        float4 w4 = ((const float4*)W)[i];
        int k = i >> 4, n = (i & 15) * 4;
        Wt_lds[n + 0][k] = f2bf(w4.x);
        Wt_lds[n + 1][k] = f2bf(w4.y);
        Wt_lds[n + 2][k] = f2bf(w4.z);
        Wt_lds[n + 3][k] = f2bf(w4.w);
    }
    // stage X tile
    if (BF16IN) {
        constexpr int K2 = K / 2;  // uints per row
        const unsigned* X = (const unsigned*)Xv;
        for (int i = t; i < 64 * K2; i += 256) {
            int r = i / K2, c = i % K2;
            unsigned val = 0;
            long row = row0 + r;
            if (row < N_NODES) val = X[row * K2 + c];
            *(unsigned*)&A_lds[r][c * 2] = val;
        }
    } else {
        constexpr int K4 = K / 4;
        const float* X = (const float*)Xv;
        for (int i = t; i < 64 * K4; i += 256) {
            int r = i / K4, c = i % K4;
            float4 val = make_float4(0.f, 0.f, 0.f, 0.f);
            long row = row0 + r;
            if (row < N_NODES) val = ((const float4*)X)[row * K4 + c];
            int cb = c * 4;
            A_lds[r][cb + 0] = f2bf(val.x);
            A_lds[r][cb + 1] = f2bf(val.y);
            A_lds[r][cb + 2] = f2bf(val.z);
            A_lds[r][cb + 3] = f2bf(val.w);
        }
    }
    __syncthreads();

    int w = t >> 6, l = t & 63;
    int m = l & 15, quad = l >> 4;
    f32x4 acc[4];
#pragma unroll
    for (int c = 0; c < 4; c++) acc[c] = (f32x4){0.f, 0.f, 0.f, 0.f};

#pragma unroll
    for (int ch = 0; ch < K / 32; ch++) {
        short8 a = *(const short8*)&A_lds[16 * w + m][32 * ch + 8 * quad];
#pragma unroll
        for (int c = 0; c < 4; c++) {
            short8 b = *(const short8*)&Wt_lds[16 * c + m][32 * ch + 8 * quad];
            acc[c] = __builtin_amdgcn_mfma_f32_16x16x32_bf16(a, b, acc[c], 0, 0, 0);
        }
    }

#pragma unroll
    for (int r = 0; r < 4; r++) {
        long node = row0 + 16 * w + quad * 4 + r;
        if (node < N_NODES) {
            float dv = dinv[node];
#pragma unroll
            for (int c = 0; c < 4; c++)
                hs[node * 64 + 16 * c + m] = f2bf(acc[c][r] * dv);
        }
    }
}

// ---------------- pull-gather (bf16 hs) + fused BN/ReLU ----------------
// One wave per node. half = lane>>5 picks edge parity, u = lane&31 picks the
// uint (2 bf16 features). 4 edges in flight per half = 8 per wave.
// LAST=false: write y (bf16 packed). LAST=true: fuse gemv3 -> hs3[i].
template<bool LAST>
__global__ __launch_bounds__(256) void gather_feat(const int* __restrict__ row_ptr,
                                                   const int* __restrict__ csr_src,
                                                   const ushort* __restrict__ hs,
                                                   const float* __restrict__ dinv,
                                                   const float* __restrict__ b,
                                                   const float* __restrict__ g,
                                                   const float* __restrict__ beta,
                                                   const float* __restrict__ m,
                                                   const float* __restrict__ v,
                                                   unsigned* __restrict__ y,
                                                   const float* __restrict__ W3,
                                                   float* __restrict__ hs3, int n) {
    int i = (blockIdx.x * 256 + threadIdx.x) >> 6;
    if (i >= n) return;
    int l = threadIdx.x & 63;
    int half = l >> 5, u = l & 31;
    const unsigned* H = (const unsigned*)hs;
    int beg = row_ptr[i], end = row_ptr[i + 1];
    float a0 = 0.f, a1 = 0.f;
    int k = beg + half;
    for (; k + 6 < end; k += 8) {
        int s0 = csr_src[k], s1 = csr_src[k + 2], s2 = csr_src[k + 4], s3 = csr_src[k + 6];
        unsigned p0 = H[s0 * 32 + u], p1 = H[s1 * 32 + u];
        unsigned p2 = H[s2 * 32 + u], p3 = H[s3 * 32 + u];
        a0 += (bf_lo(p0) + bf_lo(p1)) + (bf_lo(p2) + bf_lo(p3));
        a1 += (bf_hi(p0) + bf_hi(p1)) + (bf_hi(p2) + bf_hi(p3));
    }
    for (; k < end; k += 2) {
        unsigned p = H[csr_src[k] * 32 + u];
        a0 += bf_lo(p);
        a1 += bf_hi(p);
    }
    a0 += __shfl_xor(a0, 32, 64);
    a1 += __shfl_xor(a1, 32, 64);
    // self-loop term
    unsigned ps = H[(long)i * 32 + u];
    a0 += bf_lo(ps);
    a1 += bf_hi(ps);

    float2 bb = ((const float2*)b)[u];
    float2 gg = ((const float2*)g)[u];
    float2 be = ((const float2*)beta)[u];
    float2 mm = ((const float2*)m)[u];
    float2 vv = ((const float2*)v)[u];
    float di = dinv[i];
    float s0 = gg.x * rsqrtf(vv.x + BN_EPS_);
    float s1 = gg.y * rsqrtf(vv.y + BN_EPS_);
    float o0 = fmaxf((di * a0 + bb.x - mm.x) * s0 + be.x, 0.f);
    float o1 = fmaxf((di * a1 + bb.y - mm.y) * s1 + be.y, 0.f);

    if (LAST) {
        // each 32-lane half holds the full 64-feature vector -> dot with W3
        float2 w3 = ((const float2*)W3)[u];
        float p = o0 * w3.x + o1 * w3.y;
#pragma unroll
        for (int off = 16; off > 0; off >>= 1)
            p += __shfl_down(p, off, 32);
        if (l == 0) hs3[i] = p * di;
    } else {
        if (half == 0)
            y[(long)i * 32 + u] = (unsigned)f2bf(o0) | ((unsigned)f2bf(o1) << 16);
    }
}

// ---------------- layer-3 pull + sigmoid (8 loads in flight) ----------------
__global__ __launch_bounds__(256) void gather3(const int* __restrict__ row_ptr,
                                               const int* __restrict__ csr_src,
                                               const float* __restrict__ hs3,
                                               const float* __restrict__ dinv,
                                               const float* __restrict__ b3,
                                               float* __restrict__ out, int n) {
    int i = blockIdx.x * 256 + threadIdx.x;
    if (i >= n) return;
    int beg = row_ptr[i], end = row_ptr[i + 1];
    float s0 = hs3[i], s1 = 0.f, s2 = 0.f, s3 = 0.f;
    float s4 = 0.f, s5 = 0.f, s6 = 0.f, s7 = 0.f;
    int k = beg;
    for (; k + 8 <= end; k += 8) {
        s0 += hs3[csr_src[k]];
        s1 += hs3[csr_src[k + 1]];
        s2 += hs3[csr_src[k + 2]];
        s3 += hs3[csr_src[k + 3]];
        s4 += hs3[csr_src[k + 4]];
        s5 += hs3[csr_src[k + 5]];
        s6 += hs3[csr_src[k + 6]];
        s7 += hs3[csr_src[k + 7]];
    }
    for (; k < end; k++) s0 += hs3[csr_src[k]];
    float z = dinv[i] * (((s0 + s1) + (s2 + s3)) + ((s4 + s5) + (s6 + s7))) + b3[0];
    out[i] = 1.f / (1.f + expf(-z));
}

extern "C" void kernel_launch(void* const* d_in, const int* in_sizes, int n_in,
                              void* d_out, int out_size, void* d_ws, size_t ws_size,
                              hipStream_t stream) {
    const int N = N_NODES;
    const int E = E_EDGES;

    const float* x   = (const float*)d_in[0];
    const int*   ei  = (const int*)d_in[1];   // [2, E]: row0=src, row1=dst
    const float* W1  = (const float*)d_in[2];
    const float* b1  = (const float*)d_in[3];
    const float* W2  = (const float*)d_in[4];
    const float* b2  = (const float*)d_in[5];
    const float* W3  = (const float*)d_in[6];
    const float* b3  = (const float*)d_in[7];
    const float* g1  = (const float*)d_in[8];
    const float* bt1 = (const float*)d_in[9];
    const float* m1  = (const float*)d_in[10];
    const float* v1  = (const float*)d_in[11];
    const float* g2  = (const float*)d_in[12];
    const float* bt2 = (const float*)d_in[13];
    const float* m2  = (const float*)d_in[14];
    const float* v2  = (const float*)d_in[15];
    float* out = (float*)d_out;

    // workspace layout (4-byte units)
    int*    wsi         = (int*)d_ws;
    float*  dinv        = (float*)wsi;                 // N
    float*  hs3         = (float*)(wsi + (long)N);     // N
    int*    row_ptr     = wsi + 2L * N;                // N+1 (pad 16)
    int*    histPB      = wsi + 3L * N + 16;           // NBUCK*PB = 78200
    int*    bucket_tot  = histPB + NBUCK * PB;         // NBUCK (pad 400)
    int*    bucket_base = bucket_tot + 400;            // NBUCK+1 (pad 400)
    int*    csr_src     = bucket_base + 400;           // E
    ushort* hsb         = (ushort*)(csr_src + (long)E);   // N*64 bf16 = 32N ints
    unsigned* yb        = (unsigned*)(csr_src + (long)E + 32L * N); // N*32 uints (bf16 y)
    int*    ebuf        = (int*)hsb;                   // E ints, aliases hsb (32N==E)

    // ---- CSR build (bucketed counting sort, no global atomics) ----
    passA1_hist<<<PB, 256, 0, stream>>>(ei, histPB);
    scan_rows<<<NBUCK, 256, 0, stream>>>(histPB, bucket_tot);
    scan_totals<<<1, 512, 0, stream>>>(bucket_tot, bucket_base, row_ptr);
    passA2_scatter<<<PB, 256, 0, stream>>>(ei, histPB, bucket_base, ebuf);
    passB_place<<<NBUCK, 256, 0, stream>>>(ebuf, bucket_base, row_ptr, csr_src, dinv);

    // ---- layer 1 ----
    gemm_bf16<IN_DIM_, false><<<(N + 63) / 64, 256, 0, stream>>>(x, W1, dinv, hsb);
    gather_feat<false><<<N / 4, 256, 0, stream>>>(row_ptr, csr_src, hsb, dinv,
                                                  b1, g1, bt1, m1, v1, yb, W3, hs3, N);
    // ---- layer 2 (+ fused gemv3) ----
    gemm_bf16<HID_, true><<<(N + 63) / 64, 256, 0, stream>>>(yb, W2, dinv, hsb);
    gather_feat<true><<<N / 4, 256, 0, stream>>>(row_ptr, csr_src, hsb, dinv,
                                                 b2, g2, bt2, m2, v2, yb, W3, hs3, N);
    // ---- layer 3 ----
    gather3<<<(N + 255) / 256, 256, 0, stream>>>(row_ptr, csr_src, hs3, dinv, b3, out, N);
}